// Round 5
// baseline (38.327 us; speedup 1.0000x reference)
//
#include <hip/hip_runtime.h>

// Jacobi damped smoother: out = x + (w/k11) * (f - conv3x3(x, k)), zero padding.
// B=64, H=512, W=512, fp32.
// One wave covers a full 512-col row (8 cols/lane); halos via shfl, not memory.
// ROWS=1 row per wave -> 32768 waves (8192 blocks): maximize latency hiding;
// the 3x logical x re-reads are halo rows served by L2/L3, not HBM.

#define ROWS 1

typedef float f32x4 __attribute__((ext_vector_type(4)));

__global__ __launch_bounds__(256) void jacobi_kernel(
    const float* __restrict__ x,
    const float* __restrict__ f,
    const float* __restrict__ kA,
    float* __restrict__ out)
{
    const int tid  = blockIdx.x * blockDim.x + threadIdx.x;
    const int lane = tid & 63;
    const int wid  = tid >> 6;
    const int r0   = wid & 511;         // row (512 strips of 1 row per batch)
    const int b    = wid >> 9;
    const int c0   = lane << 3;         // 8 columns per lane

    // per-batch 3x3 kernel (uniform across the wave -> scalar broadcast)
    const float* kb = kA + b * 9;
    const float k00 = kb[0], k01 = kb[1], k02 = kb[2];
    const float k10 = kb[3], k11 = kb[4], k12 = kb[5];
    const float k20 = kb[6], k21 = kb[7], k22 = kb[8];
    const float weight = (2.0f / 3.0f) / k11;

    const size_t plane = (size_t)b << 18;       // 512*512
    const float* xb = x + plane;
    const float* fb = f + plane + ((size_t)r0 << 9) + c0;
    float*       ob = out + plane + ((size_t)r0 << 9) + c0;

    // ---- load 3 x-rows (8 wide + 2 halo slots each) + 1 f-row, all issued upfront ----
    float xr[3][10];
    #pragma unroll
    for (int q = 0; q < 3; ++q) {
        const int r = r0 - 1 + q;               // wave-uniform validity
        if (r >= 0 && r < 512) {
            const float* p = xb + ((size_t)r << 9) + c0;
            const f32x4 a = *(const f32x4*)p;
            const f32x4 c = *(const f32x4*)(p + 4);
            xr[q][1] = a.x; xr[q][2] = a.y; xr[q][3] = a.z; xr[q][4] = a.w;
            xr[q][5] = c.x; xr[q][6] = c.y; xr[q][7] = c.z; xr[q][8] = c.w;
        } else {
            #pragma unroll
            for (int c2 = 1; c2 < 9; ++c2) xr[q][c2] = 0.0f;
        }
    }
    const f32x4 f0 = *(const f32x4*)fb;
    const f32x4 f1 = *(const f32x4*)(fb + 4);

    // ---- halos via cross-lane shuffle (wave spans the full row) ----
    #pragma unroll
    for (int q = 0; q < 3; ++q) {
        float left  = __shfl_up(xr[q][8], 1);
        float right = __shfl_down(xr[q][1], 1);
        xr[q][0] = (lane == 0)  ? 0.0f : left;   // image left edge -> 0
        xr[q][9] = (lane == 63) ? 0.0f : right;  // image right edge -> 0
    }

    const float fx[8] = { f0.x, f0.y, f0.z, f0.w, f1.x, f1.y, f1.z, f1.w };

    float res[8];
    #pragma unroll
    for (int p = 0; p < 8; ++p) {
        float Ax = k00 * xr[0][p] + k01 * xr[0][p + 1] + k02 * xr[0][p + 2]
                 + k10 * xr[1][p] + k11 * xr[1][p + 1] + k12 * xr[1][p + 2]
                 + k20 * xr[2][p] + k21 * xr[2][p + 1] + k22 * xr[2][p + 2];
        res[p] = xr[1][p + 1] + weight * (fx[p] - Ax);
    }

    f32x4 v0 = { res[0], res[1], res[2], res[3] };
    f32x4 v1 = { res[4], res[5], res[6], res[7] };
    *(f32x4*)ob       = v0;
    *(f32x4*)(ob + 4) = v1;
}

extern "C" void kernel_launch(void* const* d_in, const int* in_sizes, int n_in,
                              void* d_out, int out_size, void* d_ws, size_t ws_size,
                              hipStream_t stream) {
    const float* x  = (const float*)d_in[0];
    const float* f  = (const float*)d_in[1];
    const float* kA = (const float*)d_in[2];
    float* out = (float*)d_out;

    // waves = 64 batches * 512 rows = 32768 ; threads = 2097152 ; blocks = 8192
    const int total = 64 * (512 / ROWS) * 64;
    const int block = 256;
    const int grid  = total / block;
    jacobi_kernel<<<grid, block, 0, stream>>>(x, f, kA, out);
}